// Round 5
// baseline (130.678 us; speedup 1.0000x reference)
//
#include <hip/hip_runtime.h>
#include <stdint.h>

// VQ-VAE vector quantizer, MI355X — fused single-pass MFMA kernel.
// z: (32, 256, 32, 32) fp32 ; embedding: (1024, 256) fp32
// out: [0, 8388608) quant_z (N,C,H,W) ; [8388608] vq_loss ; [8388609] commit_loss
//
//   argmin_k ||z-e_k||^2 = argmin_k ( ||e_k||^2 - 2 z.e_k )   [bf16 MFMA scores]
//   vq_loss = (sum_m (||z_m||^2 + s_min(m))) / (M*C), commit = 0.25*vq_loss
//
// Design: 256 blocks (1/CU), 128 z-rows resident in LDS (bf16, XOR-swizzled),
// A-fragments cached in VGPRs, B-fragments loaded DIRECTLY from global (L2-resident
// 512 KB Eb) with one-tile-ahead register double buffer => zero barriers in the
// score loop. Epilogue gathers E rows and writes quant_z in-block (reuses zs LDS).

#define CDIM  256
#define M_TOTAL 32768

// ws byte offsets
#define WS_EB     16777216u    // bf16[1024][256]
#define WS_ENORM  17301504u    // f32[1024]
#define WS_LOSS   19664896u    // f32

// LDS byte offsets (dynamic, 89600 total)
#define L_ZS     0u            // bf16 [128 rows][256 c], XOR-granule swizzle (dead after af-cache)
#define L_GT     0u            // epilogue: f32 gather tile [256][33]  (33792 B, overlays zs)
#define L_IDX    40960u        // epilogue: i32[128] final indices     (overlays zs tail)
#define L_TILEF  65536u        // f32[32][132] transpose staging
#define L_ENORM  82432u        // f32[1024]
#define L_ZNP    86528u        // f32[128][2]
#define L_CAND   87552u        // float2[4][64]

typedef __attribute__((ext_vector_type(8))) short bf16x8;
typedef __attribute__((ext_vector_type(4))) float f32x4;

__device__ inline unsigned short f2bf(float f) {
  uint32_t u = __float_as_uint(f);
  return (unsigned short)((u + 0x7FFFu + ((u >> 16) & 1u)) >> 16);
}

__device__ inline void load16(const void* g, void* l) {
  __builtin_amdgcn_global_load_lds((const __attribute__((address_space(1))) void*)g,
                                   (__attribute__((address_space(3))) void*)l, 16, 0, 0);
}

// E -> bf16 Eb + eNorm ; zero loss. 256 blocks x 256 thr.
__global__ void vq_prep_e(const float* __restrict__ E, char* __restrict__ ws) {
  const int w = threadIdx.x >> 6, l = threadIdx.x & 63;
  const int row = blockIdx.x * 4 + w;
  const float4 v = *(const float4*)(E + (size_t)row * CDIM + l * 4);
  ushort4 b;
  b.x = f2bf(v.x); b.y = f2bf(v.y); b.z = f2bf(v.z); b.w = f2bf(v.w);
  *(ushort4*)(ws + WS_EB + (size_t)row * 512 + l * 8) = b;
  float s = v.x * v.x + v.y * v.y + v.z * v.z + v.w * v.w;
  #pragma unroll
  for (int m = 32; m >= 1; m >>= 1) s += __shfl_xor(s, m);
  if (l == 0) ((float*)(ws + WS_ENORM))[row] = s;
  if (blockIdx.x == 0 && threadIdx.x == 0) *((float*)(ws + WS_LOSS)) = 0.f;
}

struct BTile { bf16x8 b[8][2]; };

__device__ inline void load_btile(const char* __restrict__ ebBase, int tile, BTile& bt) {
  #pragma unroll
  for (int kg = 0; kg < 8; ++kg)
    #pragma unroll
    for (int cs = 0; cs < 2; ++cs)
      bt.b[kg][cs] = *(const bf16x8*)(ebBase + (size_t)tile * 32768 + cs * 8192 + kg * 64);
}

__device__ inline void mfma_fold(const BTile& bt, const bf16x8 af[4][8],
                                 int tile, int chalf, int lrow,
                                 const float* __restrict__ eNormS,
                                 float bb[4][4], int bidx[4][4]) {
  f32x4 acc[4][2];
  #pragma unroll
  for (int rs = 0; rs < 4; ++rs)
    #pragma unroll
    for (int cs = 0; cs < 2; ++cs) acc[rs][cs] = (f32x4){0.f, 0.f, 0.f, 0.f};
  #pragma unroll
  for (int kg = 0; kg < 8; ++kg)
    #pragma unroll
    for (int rs = 0; rs < 4; ++rs)
      #pragma unroll
      for (int cs = 0; cs < 2; ++cs)
        acc[rs][cs] = __builtin_amdgcn_mfma_f32_16x16x32_bf16(af[rs][kg], bt.b[kg][cs], acc[rs][cs], 0, 0, 0);
  #pragma unroll
  for (int cs = 0; cs < 2; ++cs) {
    const int code = tile * 64 + chalf + cs * 16 + lrow;
    const float eN = eNormS[code];
    #pragma unroll
    for (int rs = 0; rs < 4; ++rs)
      #pragma unroll
      for (int i = 0; i < 4; ++i) {
        const float s = fmaf(-2.f, acc[rs][cs][i], eN);
        if (s < bb[rs][i]) { bb[rs][i] = s; bidx[rs][i] = code; }
      }
  }
}

// One block per CU: 128 z-rows; 1024 codes; argmin + loss + gather + out-write.
__global__ __launch_bounds__(256, 1)
void vq_main(const float* __restrict__ z, const float* __restrict__ E,
             char* __restrict__ ws, float* __restrict__ out) {
  extern __shared__ char lds[];
  unsigned short* zs = (unsigned short*)(lds + L_ZS);
  float* gtile       = (float*)(lds + L_GT);       // [256][33], overlays zs (epilogue)
  int*   idxS        = (int*)(lds + L_IDX);        // [128], overlays zs (epilogue)
  float* tileF       = (float*)(lds + L_TILEF);
  float* eNormS      = (float*)(lds + L_ENORM);
  float* znPart      = (float*)(lds + L_ZNP);
  float2* cand       = (float2*)(lds + L_CAND);

  const int t = threadIdx.x, w = t >> 6, l = t & 63;
  const int mt = blockIdx.x;                 // 0..255
  const int n = mt >> 3, hw0 = (mt & 7) << 7;
  const char* Eb = ws + WS_EB;

  // stage eNorm into LDS (drained by first prologue barrier)
  load16((const char*)(ws + WS_ENORM) + (w * 64 + l) * 16, (char*)eNormS + (w * 64 + l) * 16);

  // ---- prologue: z (c-major) -> zs (row-major bf16, swizzled) + |z|^2 ----
  const float* zb0 = z + (size_t)n * (CDIM * 1024) + hw0;
  const int cA = t >> 3;                     // c within 32-chunk
  const int hA = (t & 7) * 16;               // hw offset (4 float4)
  const int r2 = t >> 1, gsub = t & 1;
  float4 v0 = *(const float4*)(zb0 + (size_t)cA * 1024 + hA);
  float4 v1 = *(const float4*)(zb0 + (size_t)cA * 1024 + hA + 4);
  float4 v2 = *(const float4*)(zb0 + (size_t)cA * 1024 + hA + 8);
  float4 v3 = *(const float4*)(zb0 + (size_t)cA * 1024 + hA + 12);
  float znAcc = 0.f;
  for (int ci = 0; ci < 8; ++ci) {
    __syncthreads();                         // tileF free
    *(float4*)(tileF + cA * 132 + hA)      = v0;
    *(float4*)(tileF + cA * 132 + hA + 4)  = v1;
    *(float4*)(tileF + cA * 132 + hA + 8)  = v2;
    *(float4*)(tileF + cA * 132 + hA + 12) = v3;
    if (ci < 7) {
      const float* src = zb0 + (size_t)((ci + 1) * 32 + cA) * 1024 + hA;
      v0 = *(const float4*)(src);
      v1 = *(const float4*)(src + 4);
      v2 = *(const float4*)(src + 8);
      v3 = *(const float4*)(src + 12);
    }
    __syncthreads();                         // tileF ready
    float s[16];
    #pragma unroll
    for (int k = 0; k < 16; ++k) {
      s[k] = tileF[(gsub * 16 + k) * 132 + r2];
      znAcc += s[k] * s[k];
    }
    #pragma unroll
    for (int jj = 0; jj < 2; ++jj) {
      union { bf16x8 v; unsigned short u[8]; } pk;
      #pragma unroll
      for (int k = 0; k < 8; ++k) pk.u[k] = f2bf(s[jj * 8 + k]);
      const int g  = ci * 4 + gsub * 2 + jj;     // logical granule 0..31
      const int gp = g ^ (r2 & 7);
      *(bf16x8*)((char*)zs + r2 * 512 + gp * 16) = pk.v;
    }
  }
  znPart[r2 * 2 + gsub] = znAcc;
  __syncthreads();                           // zs complete

  // ---- cache A fragments in registers: 64 rows x K=256 per wave ----
  const int wrow = (w & 1) * 64, chalf = (w >> 1) * 32;
  const int lrow = l & 15, lk = l >> 4;
  bf16x8 af[4][8];
  #pragma unroll
  for (int rs = 0; rs < 4; ++rs) {
    const int r = wrow + rs * 16 + lrow;
    #pragma unroll
    for (int kg = 0; kg < 8; ++kg) {
      const int gp = (kg * 4 + lk) ^ (r & 7);
      af[rs][kg] = *(const bf16x8*)((const char*)zs + r * 512 + gp * 16);
    }
  }

  // ---- barrier-free main loop: 16 tiles x 64 codes, B from global (L2) ----
  float bb[4][4]; int bidx[4][4];
  #pragma unroll
  for (int rs = 0; rs < 4; ++rs)
    #pragma unroll
    for (int i = 0; i < 4; ++i) { bb[rs][i] = 3.4e38f; bidx[rs][i] = 0; }

  const char* ebBase = Eb + (size_t)(chalf + lrow) * 512 + lk * 16;
  BTile bufA, bufB;
  load_btile(ebBase, 0, bufA);
  for (int tile = 0; tile < 16; tile += 2) {
    if (tile + 1 < 16) load_btile(ebBase, tile + 1, bufB);
    mfma_fold(bufA, af, tile, chalf, lrow, eNormS, bb, bidx);
    if (tile + 2 < 16) load_btile(ebBase, tile + 2, bufA);
    mfma_fold(bufB, af, tile + 1, chalf, lrow, eNormS, bb, bidx);
  }

  // ---- reduce over 16 code-lanes, cross-wave combine ----
  #pragma unroll
  for (int rs = 0; rs < 4; ++rs)
    #pragma unroll
    for (int i = 0; i < 4; ++i)
      #pragma unroll
      for (int m = 8; m >= 1; m >>= 1) {
        const float ob = __shfl_xor(bb[rs][i], m);
        const int   oi = __shfl_xor(bidx[rs][i], m);
        if (ob < bb[rs][i] || (ob == bb[rs][i] && oi < bidx[rs][i])) { bb[rs][i] = ob; bidx[rs][i] = oi; }
      }
  if (lrow == 0) {
    #pragma unroll
    for (int rs = 0; rs < 4; ++rs)
      #pragma unroll
      for (int i = 0; i < 4; ++i) {
        float2 c; c.x = bb[rs][i]; c.y = __int_as_float(bidx[rs][i]);
        cand[w * 64 + rs * 16 + lk * 4 + i] = c;
      }
  }
  __syncthreads();                           // cand ready; all waves past af/zs reads
  if (t < 128) {
    const int half = t >> 6, rl = t & 63;
    const float2 cA0 = cand[half * 64 + rl];
    const float2 cB0 = cand[(half + 2) * 64 + rl];
    float best = cA0.x; int bi = __float_as_int(cA0.y);
    const int biB = __float_as_int(cB0.y);
    if (cB0.x < best || (cB0.x == best && biB < bi)) { best = cB0.x; bi = biB; }
    const int r = half * 64 + rl;
    idxS[r] = bi;
    float d = znPart[r * 2] + znPart[r * 2 + 1] + best;
    #pragma unroll
    for (int m = 32; m >= 1; m >>= 1) d += __shfl_xor(d, m);
    if ((t & 63) == 0) atomicAdd((float*)(ws + WS_LOSS), d);
  }
  __syncthreads();                           // idxS ready, zs region reusable

  // ---- fused gather + out-write: 4 chunks of 32 hw ----
  for (int hwc = 0; hwc < 4; ++hwc) {
    const int hwl = t >> 3, q = t & 7;
    const float4* erow = (const float4*)(E + (size_t)idxS[hwc * 32 + hwl] * CDIM);
    #pragma unroll
    for (int j = 0; j < 8; ++j) {
      const int p = q + j * 8;               // float4 index 0..63 -> c = p*4
      const float4 v = erow[p];
      gtile[(p * 4 + 0) * 33 + hwl] = v.x;
      gtile[(p * 4 + 1) * 33 + hwl] = v.y;
      gtile[(p * 4 + 2) * 33 + hwl] = v.z;
      gtile[(p * 4 + 3) * 33 + hwl] = v.w;
    }
    __syncthreads();                         // gtile ready
    float* obase = out + (size_t)n * (CDIM * 1024) + hw0 + hwc * 32;
    const int hw4 = (t & 7) * 4, c0 = t >> 3;
    #pragma unroll
    for (int j = 0; j < 8; ++j) {
      const int c = c0 + j * 32;
      float4 v;
      v.x = gtile[c * 33 + hw4 + 0];
      v.y = gtile[c * 33 + hw4 + 1];
      v.z = gtile[c * 33 + hw4 + 2];
      v.w = gtile[c * 33 + hw4 + 3];
      *(float4*)(obase + (size_t)c * 1024 + hw4) = v;
    }
    __syncthreads();                         // gtile reusable
  }
}

__global__ void vq_finalize(const char* __restrict__ ws, float* __restrict__ out) {
  if (threadIdx.x == 0 && blockIdx.x == 0) {
    const float L = *((const float*)(ws + WS_LOSS)) * (1.0f / 8388608.0f);
    out[8388608] = L;
    out[8388609] = 0.25f * L;
  }
}

extern "C" void kernel_launch(void* const* d_in, const int* in_sizes, int n_in,
                              void* d_out, int out_size, void* d_ws, size_t ws_size,
                              hipStream_t stream) {
  const float* z = (const float*)d_in[0];
  const float* E = (const float*)d_in[1];
  float* out = (float*)d_out;
  char*  ws  = (char*)d_ws;

  static const int kLds = 89600;
  (void)hipFuncSetAttribute((const void*)vq_main,
                            hipFuncAttributeMaxDynamicSharedMemorySize, kLds);

  vq_prep_e <<<256, 256, 0, stream>>>(E, ws);
  vq_main   <<<256, 256, kLds, stream>>>(z, E, ws, out);
  vq_finalize<<<1, 64, 0, stream>>>(ws, out);
}

// Round 6
// 128.895 us; speedup vs baseline: 1.0138x; 1.0138x over previous
//
#include <hip/hip_runtime.h>
#include <stdint.h>

// VQ-VAE vector quantizer, MI355X — fused MFMA kernel, 8 waves/CU.
// z: (32, 256, 32, 32) fp32 ; embedding: (1024, 256) fp32
// out: [0, 8388608) quant_z (N,C,H,W) ; [8388608] vq_loss ; [8388609] commit_loss
//
//   argmin_k ||z-e_k||^2 = argmin_k ( ||e_k||^2 - 2 z.e_k )   [bf16 MFMA scores]
//   vq_loss = (sum_m (||z_m||^2 + s_min(m))) / (M*C), commit = 0.25*vq_loss
//
// 256 blocks x 512 thr (1 block/CU, 2 waves/SIMD for latency hiding).
// 128 z-rows resident in LDS (bf16, XOR-swizzled), A-frags cached in VGPRs
// (af[4][8]), B straight from L2-resident Eb, register double-buffered.
// Wave tile 64 rows x 16 codes (w&1 = row half, w>>1 = code quarter).

#define CDIM 256

// ws byte offsets
#define WS_EB     16777216u    // bf16[1024][256]
#define WS_ENORM  17301504u    // f32[1024]
#define WS_LOSS   19664896u    // f32

// LDS byte offsets (dynamic, 92672 total)
#define L_ZS     0u            // bf16[128][256] swizzled (65536); dead after af-cache
#define L_GT     0u            // epilogue: f32[256][33] gather tile (33792, overlays zs)
#define L_IDX    40960u        // epilogue: i32[128] (overlays zs tail)
#define L_TILEF  65536u        // f32[32][132] transpose staging (16896)
#define L_ENORM  82432u        // f32[1024]
#define L_ZNP    86528u        // f32[128][4] znorm partials
#define L_CAND   88576u        // float2[4][128] per-quarter candidates

typedef __attribute__((ext_vector_type(8))) short bf16x8;
typedef __attribute__((ext_vector_type(4))) float f32x4;

__device__ inline unsigned short f2bf(float f) {
  uint32_t u = __float_as_uint(f);
  return (unsigned short)((u + 0x7FFFu + ((u >> 16) & 1u)) >> 16);
}

__device__ inline void load16(const void* g, void* l) {
  __builtin_amdgcn_global_load_lds((const __attribute__((address_space(1))) void*)g,
                                   (__attribute__((address_space(3))) void*)l, 16, 0, 0);
}

// E -> bf16 Eb + eNorm ; zero loss. 256 blocks x 256 thr.
__global__ void vq_prep_e(const float* __restrict__ E, char* __restrict__ ws) {
  const int w = threadIdx.x >> 6, l = threadIdx.x & 63;
  const int row = blockIdx.x * 4 + w;
  const float4 v = *(const float4*)(E + (size_t)row * CDIM + l * 4);
  ushort4 b;
  b.x = f2bf(v.x); b.y = f2bf(v.y); b.z = f2bf(v.z); b.w = f2bf(v.w);
  *(ushort4*)(ws + WS_EB + (size_t)row * 512 + l * 8) = b;
  float s = v.x * v.x + v.y * v.y + v.z * v.z + v.w * v.w;
  #pragma unroll
  for (int m = 32; m >= 1; m >>= 1) s += __shfl_xor(s, m);
  if (l == 0) ((float*)(ws + WS_ENORM))[row] = s;
  if (blockIdx.x == 0 && threadIdx.x == 0) *((float*)(ws + WS_LOSS)) = 0.f;
}

struct BT { bf16x8 v[8]; };   // 16 codes x K64-chunk... actually full K via kg*granule

__device__ inline void load_bt(const char* __restrict__ ebBase, int tile, BT& bt) {
  #pragma unroll
  for (int kg = 0; kg < 8; ++kg)
    bt.v[kg] = *(const bf16x8*)(ebBase + (size_t)tile * 32768 + kg * 64);
}

__device__ inline void fold_bt(const BT& bt, const bf16x8 af[4][8], int tile,
                               int qcode, const float* __restrict__ eNormS,
                               float bb[4][4], int bidx[4][4]) {
  f32x4 acc[4];
  #pragma unroll
  for (int rs = 0; rs < 4; ++rs) acc[rs] = (f32x4){0.f, 0.f, 0.f, 0.f};
  #pragma unroll
  for (int kg = 0; kg < 8; ++kg)
    #pragma unroll
    for (int rs = 0; rs < 4; ++rs)
      acc[rs] = __builtin_amdgcn_mfma_f32_16x16x32_bf16(af[rs][kg], bt.v[kg], acc[rs], 0, 0, 0);
  const int code = tile * 64 + qcode;
  const float eN = eNormS[code];
  #pragma unroll
  for (int rs = 0; rs < 4; ++rs)
    #pragma unroll
    for (int i = 0; i < 4; ++i) {
      const float s = fmaf(-2.f, acc[rs][i], eN);
      if (s < bb[rs][i]) { bb[rs][i] = s; bidx[rs][i] = code; }   // tiles ascend => first-min
    }
}

// One block per CU, 512 threads: transpose + scores + argmin + loss + gather + write.
__global__ __launch_bounds__(512, 2)
void vq_main(const float* __restrict__ z, const float* __restrict__ E,
             char* __restrict__ ws, float* __restrict__ out) {
  extern __shared__ char lds[];
  unsigned short* zs = (unsigned short*)(lds + L_ZS);
  float* gtile       = (float*)(lds + L_GT);
  int*   idxS        = (int*)(lds + L_IDX);
  float* tileF       = (float*)(lds + L_TILEF);
  float* eNormS      = (float*)(lds + L_ENORM);
  float* znPart4     = (float*)(lds + L_ZNP);
  float2* cand       = (float2*)(lds + L_CAND);

  const int t = threadIdx.x, w = t >> 6, l = t & 63;
  const int mt = blockIdx.x;                 // 0..255
  const int n = mt >> 3, hw0 = (mt & 7) << 7;
  const char* Eb = ws + WS_EB;

  // stage eNorm (waves 0..3), drained by first prologue barrier
  if (w < 4)
    load16((const char*)(ws + WS_ENORM) + (w * 64 + l) * 16, lds + L_ENORM + w * 1024);

  // ---- prologue: z (c-major) -> zs (row-major bf16, swizzled) + |z|^2 ----
  const float* zb0 = z + (size_t)n * (CDIM * 1024) + hw0;
  const int cA = t >> 4;                     // 0..31 (c within chunk)
  const int hA = (t & 15) * 8;               // 0..120
  const int row = t & 127;                   // transpose-read row (64 consecutive per wave)
  const int sub = t >> 7;                    // 0..3 (c-granule within chunk)
  float4 v0 = *(const float4*)(zb0 + (size_t)cA * 1024 + hA);
  float4 v1 = *(const float4*)(zb0 + (size_t)cA * 1024 + hA + 4);
  float znAcc = 0.f;
  for (int ci = 0; ci < 8; ++ci) {
    __syncthreads();                         // tileF free
    *(float4*)(tileF + cA * 132 + hA)     = v0;
    *(float4*)(tileF + cA * 132 + hA + 4) = v1;
    if (ci < 7) {
      const float* src = zb0 + (size_t)((ci + 1) * 32 + cA) * 1024 + hA;
      v0 = *(const float4*)(src);
      v1 = *(const float4*)(src + 4);
    }
    __syncthreads();                         // tileF ready
    float s[8];
    #pragma unroll
    for (int k = 0; k < 8; ++k) {
      s[k] = tileF[(sub * 8 + k) * 132 + row];   // 64 consecutive rows/wave: 2-way, free
      znAcc += s[k] * s[k];
    }
    union { bf16x8 v; unsigned short u[8]; } pk;
    #pragma unroll
    for (int k = 0; k < 8; ++k) pk.u[k] = f2bf(s[k]);
    const int g  = ci * 4 + sub;                 // logical granule 0..31
    const int gp = g ^ (row & 7);
    *(bf16x8*)((char*)zs + row * 512 + gp * 16) = pk.v;
  }
  znPart4[row * 4 + sub] = znAcc;
  __syncthreads();                           // zs complete

  // ---- cache A fragments: 64 rows x K=256 per wave ----
  const int wrow = (w & 1) * 64, q = w >> 1;     // row half, code quarter
  const int lrow = l & 15, lk = l >> 4;
  const int qcode = q * 16 + lrow;
  bf16x8 af[4][8];
  #pragma unroll
  for (int rs = 0; rs < 4; ++rs) {
    const int r = wrow + rs * 16 + lrow;
    #pragma unroll
    for (int kg = 0; kg < 8; ++kg) {
      const int gp = (kg * 4 + lk) ^ (r & 7);
      af[rs][kg] = *(const bf16x8*)((const char*)zs + r * 512 + gp * 16);
    }
  }

  // ---- barrier-free main loop: 16 tiles x (64 codes; this wave: 16 codes) ----
  float bb[4][4]; int bidx[4][4];
  #pragma unroll
  for (int rs = 0; rs < 4; ++rs)
    #pragma unroll
    for (int i = 0; i < 4; ++i) { bb[rs][i] = 3.4e38f; bidx[rs][i] = 0; }

  const char* ebBase = Eb + (size_t)qcode * 512 + lk * 16;
  BT bufA, bufB;
  load_bt(ebBase, 0, bufA);
  for (int tile = 0; tile < 16; tile += 2) {
    if (tile + 1 < 16) load_bt(ebBase, tile + 1, bufB);
    fold_bt(bufA, af, tile, qcode, eNormS, bb, bidx);
    if (tile + 2 < 16) load_bt(ebBase, tile + 2, bufA);
    fold_bt(bufB, af, tile + 1, qcode, eNormS, bb, bidx);
  }

  // ---- reduce over 16 code-lanes; candidates per (quarter, row) ----
  #pragma unroll
  for (int rs = 0; rs < 4; ++rs)
    #pragma unroll
    for (int i = 0; i < 4; ++i)
      #pragma unroll
      for (int m = 8; m >= 1; m >>= 1) {
        const float ob = __shfl_xor(bb[rs][i], m);
        const int   oi = __shfl_xor(bidx[rs][i], m);
        if (ob < bb[rs][i] || (ob == bb[rs][i] && oi < bidx[rs][i])) { bb[rs][i] = ob; bidx[rs][i] = oi; }
      }
  if (lrow == 0) {
    #pragma unroll
    for (int rs = 0; rs < 4; ++rs)
      #pragma unroll
      for (int i = 0; i < 4; ++i) {
        float2 c; c.x = bb[rs][i]; c.y = __int_as_float(bidx[rs][i]);
        cand[q * 128 + wrow + rs * 16 + lk * 4 + i] = c;
      }
  }
  __syncthreads();                           // cand ready; all waves done with zs

  // ---- final combine (4 quarters) + loss ----
  if (t < 128) {
    const int r = t;
    float2 c0 = cand[r];
    float best = c0.x; int bi = __float_as_int(c0.y);
    #pragma unroll
    for (int qq = 1; qq < 4; ++qq) {
      const float2 c = cand[qq * 128 + r];
      const int ci = __float_as_int(c.y);
      if (c.x < best || (c.x == best && ci < bi)) { best = c.x; bi = ci; }
    }
    idxS[r] = bi;
    float d = znPart4[r * 4] + znPart4[r * 4 + 1] + znPart4[r * 4 + 2] + znPart4[r * 4 + 3] + best;
    #pragma unroll
    for (int m = 32; m >= 1; m >>= 1) d += __shfl_xor(d, m);
    if ((t & 63) == 0) atomicAdd((float*)(ws + WS_LOSS), d);
  }
  __syncthreads();                           // idxS ready, zs region reusable

  // ---- fused gather + out-write: 4 chunks of 32 hw ----
  for (int hwc = 0; hwc < 4; ++hwc) {
    const int hwl = t >> 4, qd = t & 15;     // 32 rows x 16 lanes
    const float4* erow = (const float4*)(E + (size_t)idxS[hwc * 32 + hwl] * CDIM);
    #pragma unroll
    for (int j = 0; j < 4; ++j) {
      const int p = qd + j * 16;             // float4 index 0..63 -> c = p*4
      const float4 v = erow[p];
      gtile[(p * 4 + 0) * 33 + hwl] = v.x;
      gtile[(p * 4 + 1) * 33 + hwl] = v.y;
      gtile[(p * 4 + 2) * 33 + hwl] = v.z;
      gtile[(p * 4 + 3) * 33 + hwl] = v.w;
    }
    __syncthreads();                         // gtile ready
    float* obase = out + (size_t)n * (CDIM * 1024) + hw0 + hwc * 32;
    const int hw4 = (t & 7) * 4, c0i = t >> 3;   // 64 c-rows x 8 lanes
    #pragma unroll
    for (int j = 0; j < 4; ++j) {
      const int c = c0i + j * 64;
      float4 v;
      v.x = gtile[c * 33 + hw4 + 0];
      v.y = gtile[c * 33 + hw4 + 1];
      v.z = gtile[c * 33 + hw4 + 2];
      v.w = gtile[c * 33 + hw4 + 3];
      *(float4*)(obase + (size_t)c * 1024 + hw4) = v;
    }
    __syncthreads();                         // gtile reusable
  }
}

__global__ void vq_finalize(const char* __restrict__ ws, float* __restrict__ out) {
  if (threadIdx.x == 0 && blockIdx.x == 0) {
    const float L = *((const float*)(ws + WS_LOSS)) * (1.0f / 8388608.0f);
    out[8388608] = L;
    out[8388609] = 0.25f * L;
  }
}

extern "C" void kernel_launch(void* const* d_in, const int* in_sizes, int n_in,
                              void* d_out, int out_size, void* d_ws, size_t ws_size,
                              hipStream_t stream) {
  const float* z = (const float*)d_in[0];
  const float* E = (const float*)d_in[1];
  float* out = (float*)d_out;
  char*  ws  = (char*)d_ws;

  static const int kLds = 92672;
  (void)hipFuncSetAttribute((const void*)vq_main,
                            hipFuncAttributeMaxDynamicSharedMemorySize, kLds);

  vq_prep_e <<<256, 256, 0, stream>>>(E, ws);
  vq_main   <<<256, 512, kLds, stream>>>(z, E, ws, out);
  vq_finalize<<<1, 64, 0, stream>>>(ws, out);
}

// Round 7
// 125.337 us; speedup vs baseline: 1.0426x; 1.0284x over previous
//
#include <hip/hip_runtime.h>
#include <stdint.h>

// VQ-VAE vector quantizer, MI355X — fused MFMA kernel, 2 blocks/CU.
// z: (32, 256, 32, 32) fp32 ; embedding: (1024, 256) fp32
// out: [0, 8388608) quant_z (N,C,H,W) ; [8388608] vq_loss ; [8388609] commit_loss
//
//   argmin_k ||z-e_k||^2 = argmin_k ( ||e_k||^2 - 2 z.e_k )   [bf16 MFMA scores]
//   vq_loss = (sum_m (||z_m||^2 + s_min(m))) / (M*C), commit = 0.25*vq_loss
//
// Grid 512 x 256 thr: 64 z-rows/block, 2 independent blocks per CU so barrier
// drains in one block overlap compute in the other (r4/r5/r6 all ~56us with
// 1 block/CU regardless of structure => block-scope serialization).
// Per wave: af[4][8] A-frags cached (AGPRs), 16 codes/tile, B register-dbuf
// from L2-resident Eb. Prologue transpose double-buffered (8 barriers).

#define CDIM 256

// ws byte offsets
#define WS_EB     16777216u    // bf16[1024][256]
#define WS_ENORM  17301504u    // f32[1024]
#define WS_LOSS   19664896u    // f32

// LDS byte offsets (dynamic, 57088 total -> 2 blocks/CU)
#define L_ZS     0u            // bf16[64][256] swizzled (32768); dead after af-cache
#define L_GT     0u            // epilogue: f32[256][33] gather tile (33792, overlays zs+tf head)
#define L_TF     32768u        // f32[2][32][66] transpose dbuf (16896)
#define L_IDX    49664u        // i32[64] final indices (after gtile end 33792 ✓)
#define L_ENORM  49920u        // f32[1024]
#define L_ZNP    54016u        // f32[64][4]
#define L_CAND   55040u        // float2[4][64]

typedef __attribute__((ext_vector_type(8))) short bf16x8;
typedef __attribute__((ext_vector_type(4))) float f32x4;

__device__ inline unsigned short f2bf(float f) {
  uint32_t u = __float_as_uint(f);
  return (unsigned short)((u + 0x7FFFu + ((u >> 16) & 1u)) >> 16);
}

__device__ inline void load16(const void* g, void* l) {
  __builtin_amdgcn_global_load_lds((const __attribute__((address_space(1))) void*)g,
                                   (__attribute__((address_space(3))) void*)l, 16, 0, 0);
}

// E -> bf16 Eb + eNorm ; zero loss. 256 blocks x 256 thr.
__global__ void vq_prep_e(const float* __restrict__ E, char* __restrict__ ws) {
  const int w = threadIdx.x >> 6, l = threadIdx.x & 63;
  const int row = blockIdx.x * 4 + w;
  const float4 v = *(const float4*)(E + (size_t)row * CDIM + l * 4);
  ushort4 b;
  b.x = f2bf(v.x); b.y = f2bf(v.y); b.z = f2bf(v.z); b.w = f2bf(v.w);
  *(ushort4*)(ws + WS_EB + (size_t)row * 512 + l * 8) = b;
  float s = v.x * v.x + v.y * v.y + v.z * v.z + v.w * v.w;
  #pragma unroll
  for (int m = 32; m >= 1; m >>= 1) s += __shfl_xor(s, m);
  if (l == 0) ((float*)(ws + WS_ENORM))[row] = s;
  if (blockIdx.x == 0 && threadIdx.x == 0) *((float*)(ws + WS_LOSS)) = 0.f;
}

struct BT { bf16x8 v[8]; };    // one wave's 16 codes x K=256 tile slice

__device__ inline void load_bt(const char* __restrict__ ebBase, int tile, BT& bt) {
  #pragma unroll
  for (int kg = 0; kg < 8; ++kg)
    bt.v[kg] = *(const bf16x8*)(ebBase + (size_t)tile * 32768 + kg * 64);
}

__device__ inline void fold_bt(const BT& bt, const bf16x8 af[4][8], int tile,
                               int qcode, const float* __restrict__ eNormS,
                               float bb[4][4], int bidx[4][4]) {
  f32x4 acc[4];
  #pragma unroll
  for (int rs = 0; rs < 4; ++rs) acc[rs] = (f32x4){0.f, 0.f, 0.f, 0.f};
  #pragma unroll
  for (int kg = 0; kg < 8; ++kg)
    #pragma unroll
    for (int rs = 0; rs < 4; ++rs)
      acc[rs] = __builtin_amdgcn_mfma_f32_16x16x32_bf16(af[rs][kg], bt.v[kg], acc[rs], 0, 0, 0);
  const int code = tile * 64 + qcode;
  const float eN = eNormS[code];
  #pragma unroll
  for (int rs = 0; rs < 4; ++rs)
    #pragma unroll
    for (int i = 0; i < 4; ++i) {
      const float s = fmaf(-2.f, acc[rs][i], eN);
      if (s < bb[rs][i]) { bb[rs][i] = s; bidx[rs][i] = code; }   // tiles ascend => first-min
    }
}

// 512 blocks x 256 thr (2/CU): transpose + scores + argmin + loss + gather + write.
__global__ __launch_bounds__(256, 2)
void vq_main(const float* __restrict__ z, const float* __restrict__ E,
             char* __restrict__ ws, float* __restrict__ out) {
  extern __shared__ char lds[];
  unsigned short* zs = (unsigned short*)(lds + L_ZS);
  float* gtile       = (float*)(lds + L_GT);
  float* tf          = (float*)(lds + L_TF);       // [2][32*66]
  int*   idxS        = (int*)(lds + L_IDX);
  float* eNormS      = (float*)(lds + L_ENORM);
  float* znPart4     = (float*)(lds + L_ZNP);
  float2* cand       = (float2*)(lds + L_CAND);

  const int t = threadIdx.x, w = t >> 6, l = t & 63;
  const int mt = blockIdx.x;                 // 0..511
  const int n = mt >> 4, hw0 = (mt & 15) << 6;
  const char* Eb = ws + WS_EB;

  // stage eNorm into LDS (drained by first barrier)
  load16((const char*)(ws + WS_ENORM) + t * 16, lds + L_ENORM + t * 16);

  // ---- prologue: z (c-major) -> zs (row-major bf16, swizzled) + |z|^2 ----
  // per iter: 32 c x 64 hw staged to tf[ci&1]; transpose-read+pack; 1 barrier/iter.
  const float* zb0 = z + (size_t)n * (CDIM * 1024) + hw0;
  const int cA = t >> 3;                     // 0..31
  const int hA = (t & 7) * 8;                // 0..56
  const int row = t & 63;                    // transpose row (64 consecutive per wave pair)
  const int sub = t >> 6;                    // 0..3 c-granule quarter
  float4 v0 = *(const float4*)(zb0 + (size_t)cA * 1024 + hA);
  float4 v1 = *(const float4*)(zb0 + (size_t)cA * 1024 + hA + 4);
  float znAcc = 0.f;
  for (int ci = 0; ci < 8; ++ci) {
    float* tfc = tf + (ci & 1) * (32 * 66);
    *(float4*)(tfc + cA * 66 + hA)     = v0;
    *(float4*)(tfc + cA * 66 + hA + 4) = v1;
    if (ci < 7) {
      const float* src = zb0 + (size_t)((ci + 1) * 32 + cA) * 1024 + hA;
      v0 = *(const float4*)(src);
      v1 = *(const float4*)(src + 4);
    }
    __syncthreads();                         // tf[ci&1] ready (and tf[ci&1] readers of ci-2 done)
    float s[8];
    #pragma unroll
    for (int k = 0; k < 8; ++k) {
      s[k] = tfc[(sub * 8 + k) * 66 + row];
      znAcc += s[k] * s[k];
    }
    union { bf16x8 v; unsigned short u[8]; } pk;
    #pragma unroll
    for (int k = 0; k < 8; ++k) pk.u[k] = f2bf(s[k]);
    const int g  = ci * 4 + sub;             // logical granule 0..31
    const int gp = g ^ (row & 7);
    *(bf16x8*)((char*)zs + row * 512 + gp * 16) = pk.v;
  }
  znPart4[row * 4 + sub] = znAcc;
  __syncthreads();                           // zs complete

  // ---- cache A fragments: 64 rows x K=256 per wave (lands in AGPRs) ----
  const int lrow = l & 15, lk = l >> 4;
  const int qcode = w * 16 + lrow;           // wave owns code residue w*16.. within each 64-tile
  bf16x8 af[4][8];
  #pragma unroll
  for (int rs = 0; rs < 4; ++rs) {
    const int r = rs * 16 + lrow;
    #pragma unroll
    for (int kg = 0; kg < 8; ++kg) {
      const int gp = (kg * 4 + lk) ^ (r & 7);
      af[rs][kg] = *(const bf16x8*)((const char*)zs + r * 512 + gp * 16);
    }
  }

  // ---- barrier-free main loop: 16 tiles x 64 codes (16 per wave) ----
  float bb[4][4]; int bidx[4][4];
  #pragma unroll
  for (int rs = 0; rs < 4; ++rs)
    #pragma unroll
    for (int i = 0; i < 4; ++i) { bb[rs][i] = 3.4e38f; bidx[rs][i] = 0; }

  const char* ebBase = Eb + (size_t)qcode * 512 + lk * 16;
  BT bufA, bufB;
  load_bt(ebBase, 0, bufA);
  for (int tile = 0; tile < 16; tile += 2) {
    if (tile + 1 < 16) load_bt(ebBase, tile + 1, bufB);
    fold_bt(bufA, af, tile, qcode, eNormS, bb, bidx);
    if (tile + 2 < 16) load_bt(ebBase, tile + 2, bufA);
    fold_bt(bufB, af, tile + 1, qcode, eNormS, bb, bidx);
  }

  // ---- reduce over the 16 code-lanes ----
  #pragma unroll
  for (int rs = 0; rs < 4; ++rs)
    #pragma unroll
    for (int i = 0; i < 4; ++i)
      #pragma unroll
      for (int m = 8; m >= 1; m >>= 1) {
        const float ob = __shfl_xor(bb[rs][i], m);
        const int   oi = __shfl_xor(bidx[rs][i], m);
        if (ob < bb[rs][i] || (ob == bb[rs][i] && oi < bidx[rs][i])) { bb[rs][i] = ob; bidx[rs][i] = oi; }
      }
  if (lrow == 0) {
    #pragma unroll
    for (int rs = 0; rs < 4; ++rs)
      #pragma unroll
      for (int i = 0; i < 4; ++i) {
        float2 c; c.x = bb[rs][i]; c.y = __int_as_float(bidx[rs][i]);
        cand[w * 64 + rs * 16 + lk * 4 + i] = c;
      }
  }
  __syncthreads();                           // cand ready; zs dead

  // ---- final combine (4 code-quarters) + loss ----
  if (t < 64) {
    const int r = t;
    float2 c0 = cand[r];
    float best = c0.x; int bi = __float_as_int(c0.y);
    #pragma unroll
    for (int qq = 1; qq < 4; ++qq) {
      const float2 c = cand[qq * 64 + r];
      const int ci = __float_as_int(c.y);
      if (c.x < best || (c.x == best && ci < bi)) { best = c.x; bi = ci; }
    }
    idxS[r] = bi;
    float d = znPart4[r * 4] + znPart4[r * 4 + 1] + znPart4[r * 4 + 2] + znPart4[r * 4 + 3] + best;
    #pragma unroll
    for (int m = 32; m >= 1; m >>= 1) d += __shfl_xor(d, m);
    if (t == 0) atomicAdd((float*)(ws + WS_LOSS), d);
  }
  __syncthreads();                           // idxS ready, zs/tf region reusable as gtile

  // ---- fused gather + out-write: 2 chunks of 32 hw ----
  for (int hwc = 0; hwc < 2; ++hwc) {
    const int hwl = t >> 3, qd = t & 7;      // 32 rows x 8 lanes
    const float4* erow = (const float4*)(E + (size_t)idxS[hwc * 32 + hwl] * CDIM);
    #pragma unroll
    for (int j = 0; j < 8; ++j) {
      const int p = qd + j * 8;              // float4 index 0..63 -> c = p*4
      const float4 v = erow[p];
      gtile[(p * 4 + 0) * 33 + hwl] = v.x;
      gtile[(p * 4 + 1) * 33 + hwl] = v.y;
      gtile[(p * 4 + 2) * 33 + hwl] = v.z;
      gtile[(p * 4 + 3) * 33 + hwl] = v.w;
    }
    __syncthreads();                         // gtile ready
    float* obase = out + (size_t)n * (CDIM * 1024) + hw0 + hwc * 32;
    const int hw4 = (t & 7) * 4, c0i = t >> 3;   // 32 c-rows x 8 lanes
    #pragma unroll
    for (int j = 0; j < 8; ++j) {
      const int c = c0i + j * 32;
      float4 v;
      v.x = gtile[c * 33 + hw4 + 0];
      v.y = gtile[c * 33 + hw4 + 1];
      v.z = gtile[c * 33 + hw4 + 2];
      v.w = gtile[c * 33 + hw4 + 3];
      *(float4*)(obase + (size_t)c * 1024 + hw4) = v;
    }
    __syncthreads();                         // gtile reusable
  }
}

__global__ void vq_finalize(const char* __restrict__ ws, float* __restrict__ out) {
  if (threadIdx.x == 0 && blockIdx.x == 0) {
    const float L = *((const float*)(ws + WS_LOSS)) * (1.0f / 8388608.0f);
    out[8388608] = L;
    out[8388609] = 0.25f * L;
  }
}

extern "C" void kernel_launch(void* const* d_in, const int* in_sizes, int n_in,
                              void* d_out, int out_size, void* d_ws, size_t ws_size,
                              hipStream_t stream) {
  const float* z = (const float*)d_in[0];
  const float* E = (const float*)d_in[1];
  float* out = (float*)d_out;
  char*  ws  = (char*)d_ws;

  static const int kLds = 57088;
  (void)hipFuncSetAttribute((const void*)vq_main,
                            hipFuncAttributeMaxDynamicSharedMemorySize, kLds);

  vq_prep_e <<<256, 256, 0, stream>>>(E, ws);
  vq_main   <<<512, 256, kLds, stream>>>(z, E, ws, out);
  vq_finalize<<<1, 64, 0, stream>>>(ws, out);
}